// Round 1
// baseline (18418.491 us; speedup 1.0000x reference)
//
#include <hip/hip_runtime.h>
#include <math.h>

// Problem constants
#define BB_  64      // batch
#define TT_  512     // max timesteps
#define DD_  1024    // emb
#define HH_  1024    // hid
#define GG_  4096    // 4*HH_

// ---------------------------------------------------------------------------
// Phase-1 GEMM:  C[m][n] = sum_k A[m][k] * Bw[n][k]
//   A rows: A + m*lda (K=1024 contiguous per row)
//   Bw: [4096][1024] row-major (weights)
//   Also reused for the per-step fallback (M=64, strided A rows).
// BM=BN=128, BK=16, 256 threads, 8x8 micro-tile.
// ---------------------------------------------------------------------------
__global__ __launch_bounds__(256)
void gemm_nt_f32(const float* __restrict__ A, long lda, int M,
                 const float* __restrict__ Bw,
                 float* __restrict__ C, long ldc)
{
    __shared__ __align__(16) float As[16][132];
    __shared__ __align__(16) float Bs[16][132];
    const int tid = threadIdx.x;
    const long m0 = (long)blockIdx.x * 128;
    const long n0 = (long)blockIdx.y * 128;
    const int tx = tid & 15;        // n-dir
    const int ty = tid >> 4;        // m-dir
    const int sr = tid >> 2;        // staging row 0..63
    const int sc = (tid & 3) << 2;  // staging k-col {0,4,8,12}

    float acc[8][8];
#pragma unroll
    for (int i = 0; i < 8; ++i)
#pragma unroll
        for (int j = 0; j < 8; ++j) acc[i][j] = 0.f;

    for (int k0 = 0; k0 < 1024; k0 += 16) {
#pragma unroll
        for (int rr = 0; rr < 2; ++rr) {
            long arow = m0 + sr + rr * 64;
            float4 v = make_float4(0.f, 0.f, 0.f, 0.f);
            if ((int)arow < M)
                v = *(const float4*)(A + arow * lda + k0 + sc);
            As[sc + 0][sr + rr * 64] = v.x;
            As[sc + 1][sr + rr * 64] = v.y;
            As[sc + 2][sr + rr * 64] = v.z;
            As[sc + 3][sr + rr * 64] = v.w;

            long bcol = n0 + sr + rr * 64;  // always < 4096
            float4 w = *(const float4*)(Bw + bcol * 1024 + k0 + sc);
            Bs[sc + 0][sr + rr * 64] = w.x;
            Bs[sc + 1][sr + rr * 64] = w.y;
            Bs[sc + 2][sr + rr * 64] = w.z;
            Bs[sc + 3][sr + rr * 64] = w.w;
        }
        __syncthreads();
#pragma unroll
        for (int k = 0; k < 16; ++k) {
            float4 a0 = *(const float4*)&As[k][ty * 8];
            float4 a1 = *(const float4*)&As[k][ty * 8 + 4];
            float4 b0 = *(const float4*)&Bs[k][tx * 8];
            float4 b1 = *(const float4*)&Bs[k][tx * 8 + 4];
            float av[8] = {a0.x, a0.y, a0.z, a0.w, a1.x, a1.y, a1.z, a1.w};
            float bv[8] = {b0.x, b0.y, b0.z, b0.w, b1.x, b1.y, b1.z, b1.w};
#pragma unroll
            for (int i = 0; i < 8; ++i)
#pragma unroll
                for (int j = 0; j < 8; ++j)
                    acc[i][j] += av[i] * bv[j];
        }
        __syncthreads();
    }
#pragma unroll
    for (int i = 0; i < 8; ++i) {
        long row = m0 + ty * 8 + i;
        if ((int)row < M) {
            float4 o0 = make_float4(acc[i][0], acc[i][1], acc[i][2], acc[i][3]);
            float4 o1 = make_float4(acc[i][4], acc[i][5], acc[i][6], acc[i][7]);
            *(float4*)(C + row * ldc + n0 + tx * 8)     = o0;
            *(float4*)(C + row * ldc + n0 + tx * 8 + 4) = o1;
        }
    }
}

// ---------------------------------------------------------------------------
// Fused recurrent step: gh GEMM (3 needed gates only: i, g, o) + cell math.
// grid = 256 blocks (4 h-columns each), 256 threads (4 waves, lane = batch).
// h stored transposed & float4-packed: h4[k4][b] packs h[4*k4 .. 4*k4+3][b].
// k-range split across the 4 waves; W_hh read at wave-uniform addresses
// (-> scalar loads); partial dots reduced through LDS; cell finished in-block.
// ---------------------------------------------------------------------------
__global__ __launch_bounds__(256)
void lstm_step(const float4* __restrict__ h_in,   // [256][64] float4
               float4* __restrict__ h_out,        // [256][64] float4
               float* __restrict__ cbuf,          // [1024][64]
               const float* __restrict__ gi,      // row b at gi + b*gstride
               long gstride,
               const float* __restrict__ Whh,     // [4096][1024]
               const int* __restrict__ lengths,   // [64]
               float* __restrict__ seq,           // d_out: [64][512][1024]
               int t)
{
    const int tid  = threadIdx.x;
    const int h0   = blockIdx.x << 2;   // 4 h-columns per block
    const int wave = tid >> 6;
    const int lane = tid & 63;          // = batch

    __shared__ float red[4][12][72];    // [wave][row][b] (+pad)
    __shared__ float gix[4][4][68];     // [gate][hl][b]  (+pad)

    // ---- prefetch gi (independent of the GEMM loop) ----
    {
        const int pb = tid >> 2, pg = tid & 3;
        const float4 gv = *reinterpret_cast<const float4*>(
            gi + (long)pb * gstride + pg * 1024 + h0);
        gix[pg][0][pb] = gv.x;
        gix[pg][1][pb] = gv.y;
        gix[pg][2][pb] = gv.z;
        gix[pg][3][pb] = gv.w;
    }

    // ---- gh partial dot-products over this wave's k-quarter ----
    float acc[12];
#pragma unroll
    for (int r = 0; r < 12; ++r) acc[r] = 0.f;

    const int kb4 = __builtin_amdgcn_readfirstlane(wave << 6);  // k4 base
    const float4* hq = h_in + (size_t)kb4 * 64 + lane;
    const float* wi = Whh + ((size_t)(h0))        * 1024 + (kb4 << 2);
    const float* wg = Whh + ((size_t)(2048 + h0)) * 1024 + (kb4 << 2);
    const float* wo = Whh + ((size_t)(3072 + h0)) * 1024 + (kb4 << 2);

    for (int k4 = 0; k4 < 64; ++k4) {
        const float4 hv = hq[(size_t)k4 * 64];
#pragma unroll
        for (int d = 0; d < 4; ++d) {
            float4 a = *(const float4*)(wi + (size_t)d * 1024 + k4 * 4);
            acc[d * 3 + 0] += hv.x * a.x + hv.y * a.y + hv.z * a.z + hv.w * a.w;
            float4 b = *(const float4*)(wg + (size_t)d * 1024 + k4 * 4);
            acc[d * 3 + 1] += hv.x * b.x + hv.y * b.y + hv.z * b.z + hv.w * b.w;
            float4 c = *(const float4*)(wo + (size_t)d * 1024 + k4 * 4);
            acc[d * 3 + 2] += hv.x * c.x + hv.y * c.y + hv.z * c.z + hv.w * c.w;
        }
    }

#pragma unroll
    for (int r = 0; r < 12; ++r) red[wave][r][lane] = acc[r];
    __syncthreads();

    // ---- cell math: thread -> (b = tid>>2, hl = tid&3), h = h0+hl ----
    const int cb = tid >> 2;
    const int hl = tid & 3;

    float h_i = red[0][hl * 3 + 0][cb] + red[1][hl * 3 + 0][cb] +
                red[2][hl * 3 + 0][cb] + red[3][hl * 3 + 0][cb];
    float h_g = red[0][hl * 3 + 1][cb] + red[1][hl * 3 + 1][cb] +
                red[2][hl * 3 + 1][cb] + red[3][hl * 3 + 1][cb];
    float h_o = red[0][hl * 3 + 2][cb] + red[1][hl * 3 + 2][cb] +
                red[2][hl * 3 + 2][cb] + red[3][hl * 3 + 2][cb];

    float i_i = gix[0][hl][cb];
    float i_f = gix[1][hl][cb];
    float i_g = gix[2][hl][cb];
    float i_o = gix[3][hl][cb];

    float gx_i = 1.f / (1.f + expf(-i_i));
    float fx_i = gx_i * (1.f - gx_i);
    float gx_f = 1.f / (1.f + expf(-i_f));
    float gx_o = 1.f / (1.f + expf(-i_o));
    float fx_o = gx_o * (1.f - gx_o);
    float gx_c = tanhf(i_g);
    float fx_c = 1.f - gx_c * gx_c;
    float g_c  = gx_i * gx_c;
    float g_ct = tanhf(g_c);
    float g_h  = gx_o * g_ct;

    float c_old = cbuf[(size_t)(h0 + hl) * 64 + cb];
    float Bt = gx_f * c_old;
    float Dt = gx_c * fx_i * h_i + gx_i * fx_c * h_g;
    float sech2 = 1.f - g_ct * g_ct;
    float Et = gx_o * sech2 * gx_f * c_old;
    float Ft = gx_o * sech2 * Dt + fx_o * g_ct * h_o;

    float h_new = Et + Ft + ((t == 0) ? g_h : 0.f);
    float c_new = Bt + Dt + ((t == 0) ? g_c : 0.f);

    const float* hin_s = (const float*)h_in;
    float hprev = hin_s[(size_t)blockIdx.x * 256 + cb * 4 + hl];

    bool msk = (t < lengths[cb]);
    float h2 = msk ? h_new : hprev;
    float c2 = msk ? c_new : c_old;

    cbuf[(size_t)(h0 + hl) * 64 + cb] = c2;
    ((float*)h_out)[(size_t)blockIdx.x * 256 + cb * 4 + hl] = h2;
    seq[(size_t)cb * TT_ * HH_ + (size_t)t * HH_ + h0 + hl] = h2;
}

// ---------------------------------------------------------------------------
__global__ void zero_hc(float* __restrict__ hbuf0, float* __restrict__ cb)
{
    int i = blockIdx.x * 256 + threadIdx.x;   // grid 256*256 = 65536
    hbuf0[i] = 0.f;
    cb[i]    = 0.f;
}

__global__ void h_final_k(const float* __restrict__ hbuf,  // buf0, packed
                          float* __restrict__ outf)        // [64][1024]
{
    int b = blockIdx.x;
    for (int h = threadIdx.x; h < 1024; h += 256)
        outf[(size_t)b * 1024 + h] =
            hbuf[(size_t)(h >> 2) * 256 + b * 4 + (h & 3)];
}

// ---------------------------------------------------------------------------
extern "C" void kernel_launch(void* const* d_in, const int* in_sizes, int n_in,
                              void* d_out, int out_size, void* d_ws, size_t ws_size,
                              hipStream_t stream)
{
    const float* x   = (const float*)d_in[0];
    const int*   len = (const int*)d_in[1];
    const float* Wih = (const float*)d_in[2];
    const float* Whh = (const float*)d_in[3];
    float* out = (float*)d_out;

    // ws layout: h double-buffer (2 x 64K floats, transposed float4-packed),
    //            c (64K floats), then gi_all (512 MiB) or gi_buf (1 MiB).
    float* hbase = (float*)d_ws;
    float* cb    = hbase + 2 * 65536;
    float* gi    = hbase + 3 * 65536;

    const size_t needA = (size_t)3 * 65536 * 4 + (size_t)32768 * 4096 * 4;
    const bool pathA = (ws_size >= needA);

    zero_hc<<<dim3(256), dim3(256), 0, stream>>>(hbase, cb);

    if (pathA) {
        // gi_all[n = b*T+t][g] = x[n][:] . W_ih[g][:]
        gemm_nt_f32<<<dim3(256, 32), dim3(256), 0, stream>>>(
            x, 1024, 32768, Wih, gi, 4096);
    }

    for (int t = 0; t < 512; ++t) {
        const float* gstep;
        long gstride;
        if (pathA) {
            gstep = gi + (size_t)t * 4096;
            gstride = (long)TT_ * 4096;
        } else {
            gemm_nt_f32<<<dim3(1, 32), dim3(256), 0, stream>>>(
                x + (size_t)t * 1024, (long)TT_ * 1024, 64, Wih, gi, 4096);
            gstep = gi;
            gstride = 4096;
        }
        const float4* hin  = (const float4*)(hbase + (t & 1) * 65536);
        float4*       hout = (float4*)(hbase + ((t + 1) & 1) * 65536);
        lstm_step<<<dim3(256), dim3(256), 0, stream>>>(
            hin, hout, cb, gstep, gstride, Whh, len, out, t);
    }

    // after t=511 the final h lives in buffer 0
    h_final_k<<<dim3(64), dim3(256), 0, stream>>>(
        hbase, out + (size_t)BB_ * TT_ * HH_);
}